// Round 1
// 709.343 us; speedup vs baseline: 1.0395x; 1.0395x over previous
//
#include <hip/hip_runtime.h>

// BaseProtonet: inv_d[n,p] = 1/(mse(f_n,proto_p)+1e-5), labels[n] = plabels[argmax_p inv_d]
// msed = ||f||^2 - 2 f.p + ||p||^2  (= 64*mse), argmax inv_d == argmin msed.
//
// Round 3: kill the L2 prototype-refetch bottleneck.
//  Round-2 PMC showed VGPR_Count=64 -> compiler rematerialized the pr[64] proto
//  loads inside the row loop => 64KB of L1/L2 proto traffic per block-row
//  (~16.8 GB total ~= 490us at 34.5 TB/s L2 ~= the measured 520us). HBM was 8%,
//  VALUBusy 34%: L2-BW bound, not compute/HBM bound.
//  - asm-pin pr[k] into VGPRs (opaque to remat). __launch_bounds__(256,3) gives
//    a ~168-VGPR cap so pin + 4-row batching fits without spilling.
//  - 4 rows per iteration: barriers and thread0 combine amortized 4x, and the
//    shuffle-reduce chains for 4 rows pipeline instead of serializing.
//  - merged top-2 butterfly: single 6-step chain carrying (min,2nd-min), and the
//    cross-wave combine runs on 4 parallel lanes (one per row).
//  fp32 arithmetic order, MARGIN=0.125 rescue policy, and the fp64 rescue recipe
//  are bit-identical to the validated round-2 kernel.

#define PROTOS 256
#define DIM 64
#define MARGIN 0.125f
#define RB 4

template <int R>
__device__ __forceinline__ void do_group(
    int row0,
    const float* __restrict__ feats,
    const int* __restrict__ plabels,
    float* __restrict__ out_inv,
    float* __restrict__ out_lab,
    const float (&pr)[DIM], double p2d, float p2f,
    unsigned int (*s_m1)[4], unsigned int (*s_m2)[4],
    int* s_resc, double* s_dval, int* s_didx)
{
    const int p    = threadIdx.x;
    const int lane = threadIdx.x & 63;
    const int wid  = threadIdx.x >> 6;

    // ||f||^2 for R rows: lane load + R interleaved xor butterflies (identical
    // per-row op order to the validated kernel; chains pipeline across rows).
    float fs[R];
    #pragma unroll
    for (int r = 0; r < R; ++r) {
        float fv = feats[(size_t)(row0 + r) * DIM + lane];
        fs[r] = fv * fv;
    }
    #pragma unroll
    for (int s = 32; s > 0; s >>= 1) {
        #pragma unroll
        for (int r = 0; r < R; ++r) fs[r] += __shfl_xor(fs[r], s, 64);
    }

    // dot(f_r, proto_p): 4 accumulators per row, pr from pinned VGPRs.
    float a[R][4];
    #pragma unroll
    for (int r = 0; r < R; ++r) { a[r][0] = a[r][1] = a[r][2] = a[r][3] = 0.f; }
    #pragma unroll
    for (int i = 0; i < DIM / 4; ++i) {
        #pragma unroll
        for (int r = 0; r < R; ++r) {
            float4 x = ((const float4*)(feats + (size_t)(row0 + r) * DIM))[i];
            a[r][0] = fmaf(x.x, pr[4 * i + 0], a[r][0]);
            a[r][1] = fmaf(x.y, pr[4 * i + 1], a[r][1]);
            a[r][2] = fmaf(x.z, pr[4 * i + 2], a[r][2]);
            a[r][3] = fmaf(x.w, pr[4 * i + 3], a[r][3]);
        }
    }

    // msed, inv_d store, packed argmin keys.
    unsigned int m1[R], m2[R];
    #pragma unroll
    for (int r = 0; r < R; ++r) {
        float cross = (a[r][0] + a[r][1]) + (a[r][2] + a[r][3]);
        float msed  = fs[r] - 2.0f * cross + p2f;
        out_inv[(size_t)(row0 + r) * PROTOS + p] =
            1.0f / (msed * (1.0f / 64.0f) + 1e-5f);
        m1[r] = (__float_as_uint(msed) & 0xFFFFFF00u) | (unsigned int)p;
        m2[r] = 0xFFFFFFFFu;
    }

    // Merged (min, 2nd-min) butterfly — one 6-step chain per row, rows pipelined.
    // Keys are distinct (proto idx in low 8 bits), so 2nd-min is well-defined.
    #pragma unroll
    for (int s = 32; s > 0; s >>= 1) {
        #pragma unroll
        for (int r = 0; r < R; ++r) {
            unsigned int o1 = __shfl_xor(m1[r], s, 64);
            unsigned int o2 = __shfl_xor(m2[r], s, 64);
            unsigned int hi  = (m1[r] > o1) ? m1[r] : o1;
            unsigned int lo  = (m1[r] < o1) ? m1[r] : o1;
            unsigned int mn2 = (m2[r] < o2) ? m2[r] : o2;
            m1[r] = lo;
            m2[r] = (hi < mn2) ? hi : mn2;
        }
    }
    if (lane == 0) {
        #pragma unroll
        for (int r = 0; r < R; ++r) { s_m1[r][wid] = m1[r]; s_m2[r][wid] = m2[r]; }
    }
    __syncthreads();

    // Cross-wave combine: one lane per row (parallel, was serial thread0).
    if (threadIdx.x < R) {
        const int r = threadIdx.x;
        unsigned int b1 = 0xFFFFFFFFu, b2 = 0xFFFFFFFFu;
        #pragma unroll
        for (int w = 0; w < 4; ++w) {
            unsigned int u1 = s_m1[r][w], u2 = s_m2[r][w];
            unsigned int hi  = (b1 > u1) ? b1 : u1;
            unsigned int lo2 = (b2 < u2) ? b2 : u2;
            b1 = (b1 < u1) ? b1 : u1;
            b2 = (hi < lo2) ? hi : lo2;
        }
        float v1 = __uint_as_float(b1 & 0xFFFFFF00u);
        float v2 = __uint_as_float(b2 & 0xFFFFFF00u);
        int resc = (v2 - v1) < MARGIN;
        s_resc[r] = resc;
        if (!resc) out_lab[row0 + r] = (float)plabels[b1 & 0xFFu];
    }
    __syncthreads();

    // fp64 rescue for near-ties (~1.4% of rows) — EXACT validated recipe.
    // s_resc[] is block-uniform, so the barriers inside are safe.
    for (int r = 0; r < R; ++r) {
        if (!s_resc[r]) continue;
        const int row = row0 + r;
        const float* frow = feats + (size_t)row * DIM;

        float fl   = frow[lane];
        double fsd = (double)fl * (double)fl;
        #pragma unroll
        for (int s = 32; s > 0; s >>= 1) fsd += __shfl_xor(fsd, s, 64);

        double d0 = 0.0, d1 = 0.0, d2 = 0.0, d3 = 0.0;
        #pragma unroll
        for (int k = 0; k < DIM; k += 4) {
            d0 = fma((double)frow[k + 0], (double)pr[k + 0], d0);
            d1 = fma((double)frow[k + 1], (double)pr[k + 1], d1);
            d2 = fma((double)frow[k + 2], (double)pr[k + 2], d2);
            d3 = fma((double)frow[k + 3], (double)pr[k + 3], d3);
        }
        double crossd = (d0 + d1) + (d2 + d3);
        double msedd  = fsd - 2.0 * crossd + p2d;

        double bv = msedd;
        int    bi = p;
        #pragma unroll
        for (int s = 32; s > 0; s >>= 1) {
            double ov = __shfl_xor(bv, s, 64);
            int    oi = __shfl_xor(bi, s, 64);
            if (ov < bv || (ov == bv && oi < bi)) { bv = ov; bi = oi; }
        }
        if (lane == 0) { s_dval[wid] = bv; s_didx[wid] = bi; }
        __syncthreads();
        if (threadIdx.x == 0) {
            double v = s_dval[0];
            int    i = s_didx[0];
            #pragma unroll
            for (int w = 1; w < 4; ++w) {
                if (s_dval[w] < v || (s_dval[w] == v && s_didx[w] < i)) {
                    v = s_dval[w]; i = s_didx[w];
                }
            }
            out_lab[row] = (float)plabels[i];
        }
        __syncthreads();
    }
}

__global__ __launch_bounds__(256, 3)
void protonet_kernel(const float* __restrict__ feats,
                     const float* __restrict__ protos,
                     const int* __restrict__ plabels,
                     float* __restrict__ out_inv,
                     float* __restrict__ out_lab,
                     int rows_total)
{
    const int p = threadIdx.x;

    // Prototype row into 64 fp32 VGPRs...
    float pr[DIM];
    {
        const float4* prv = (const float4*)(protos + p * DIM);
        #pragma unroll
        for (int i = 0; i < DIM / 4; ++i) {
            float4 v = prv[i];
            pr[4 * i + 0] = v.x; pr[4 * i + 1] = v.y;
            pr[4 * i + 2] = v.z; pr[4 * i + 3] = v.w;
        }
    }
    // ...and PIN them there. Round-2 PMC (VGPR_Count=64) proved the compiler
    // rematerialized these loads per row => 16.8 GB of L2 proto traffic. The
    // empty asm makes each pr[k] opaque: it must stay in a VGPR.
    #pragma unroll
    for (int k = 0; k < DIM; ++k) asm volatile("" : "+v"(pr[k]));

    // p2 in fp64 (exact round-1 order) and fp32 (main pass).
    double p2d = 0.0;
    #pragma unroll
    for (int k = 0; k < DIM; ++k) p2d = fma((double)pr[k], (double)pr[k], p2d);
    float p2f = (float)p2d;

    __shared__ unsigned int s_m1[RB][4], s_m2[RB][4];
    __shared__ int    s_resc[RB];
    __shared__ double s_dval[4];
    __shared__ int    s_didx[4];

    const int ngroups = rows_total / RB;
    for (int g = blockIdx.x; g < ngroups; g += gridDim.x) {
        do_group<RB>(g * RB, feats, plabels, out_inv, out_lab,
                     pr, p2d, p2f, s_m1, s_m2, s_resc, s_dval, s_didx);
    }

    // Tail rows (rows_total % RB) — block 0, single-row path, same code.
    if (blockIdx.x == 0) {
        for (int row = ngroups * RB; row < rows_total; ++row) {
            do_group<1>(row, feats, plabels, out_inv, out_lab,
                        pr, p2d, p2f, s_m1, s_m2, s_resc, s_dval, s_didx);
        }
    }
}

extern "C" void kernel_launch(void* const* d_in, const int* in_sizes, int n_in,
                              void* d_out, int out_size, void* d_ws, size_t ws_size,
                              hipStream_t stream) {
    const float* feats  = (const float*)d_in[0];
    const float* protos = (const float*)d_in[1];
    const int*   plab   = (const int*)d_in[2];
    const int rows = in_sizes[0] / DIM;

    float* out_inv = (float*)d_out;
    float* out_lab = out_inv + (size_t)rows * PROTOS;

    dim3 grid(2048), block(256);
    hipLaunchKernelGGL(protonet_kernel, grid, block, 0, stream,
                       feats, protos, plab, out_inv, out_lab, rows);
}